// Round 15
// baseline (460.698 us; speedup 1.0000x reference)
//
#include <hip/hip_runtime.h>
#include <hip/hip_fp16.h>
#include <math.h>

#define NB 64
#define DIM 128
#define ETOT 1048576
#define EPG 16384   // edges-per-graph region (ETOT / NB)
#define EPT 16      // edges per thread in 1024-thread per-graph kernels

static const int NS_H[6] = {1024, 820, 656, 525, 420, 336};

typedef _Float16 f16x8 __attribute__((ext_vector_type(8)));
typedef float f32x4 __attribute__((ext_vector_type(4)));
typedef float f32x2 __attribute__((ext_vector_type(2)));
typedef unsigned short ushortT;

// order-preserving float->uint transform for atomicMax
__device__ __forceinline__ unsigned fxform(float f) {
    int b = __float_as_int(f);
    return (b >= 0) ? ((unsigned)b | 0x80000000u) : ~(unsigned)b;
}
__device__ __forceinline__ float fxinv(unsigned u) {
    int b = (u & 0x80000000u) ? (int)(u ^ 0x80000000u) : (int)~u;
    return __int_as_float(b);
}
// packed-half max/add via float roundtrip (no __hmax2/__hadd2 on this ROCm)
__device__ __forceinline__ unsigned hmax2u(unsigned a, unsigned b) {
    float2 fa = __half22float2(*(__half2*)&a);
    float2 fb = __half22float2(*(__half2*)&b);
    __half2 r = __floats2half2_rn(fmaxf(fa.x, fb.x), fmaxf(fa.y, fb.y));
    return *(unsigned*)&r;
}
__device__ __forceinline__ unsigned hadd2u(unsigned a, unsigned b) {
    float2 fa = __half22float2(*(__half2*)&a);
    float2 fb = __half22float2(*(__half2*)&b);
    __half2 r = __floats2half2_rn(fa.x + fb.x, fa.y + fb.y);
    return *(unsigned*)&r;
}

// ------- init: edges->sd(packed local), histogram, scan, scatter eidx(u16), dinv, invn, W->fp16 ---
__global__ __launch_bounds__(1024) void init_kernel(const int* __restrict__ ei,
                                  unsigned* __restrict__ sd,
                                  ushortT* __restrict__ eidx, int* __restrict__ eoff,
                                  int* __restrict__ cnt, float* __restrict__ dinv,
                                  float* __restrict__ invn, const float* __restrict__ pw0,
                                  unsigned* __restrict__ maxb, float* __restrict__ sumb,
                                  const float* __restrict__ cw0, const float* __restrict__ cw1,
                                  const float* __restrict__ cw2, const float* __restrict__ cw3,
                                  const float* __restrict__ cw4, __half* __restrict__ W16) {
    __shared__ int hs[1024], hc[1024], cur[1024];
    __shared__ float dv[1024];
    __shared__ float shf[128];
    __shared__ int wsum[16];
    int g = blockIdx.x, t = threadIdx.x;
    int lane = t & 63, wv = t >> 6;
    hs[t] = 0; hc[t] = 0;
    int idx = g * 1024 + t;
    if (idx < 5 * NB * 128) { maxb[idx] = 0x007FFFFFu; sumb[idx] = 0.f; }
    if (g < 5) {   // fp16 copy of this layer's weight matrix
        const float* wsrc = (g == 0) ? cw0 : (g == 1) ? cw1 : (g == 2) ? cw2
                           : (g == 3) ? cw3 : cw4;
        for (int i = t; i < 16384; i += 1024)
            W16[g * 16384 + i] = __float2half(wsrc[i]);
    }
    __syncthreads();
    int b0 = g * EPG;
    int sr[EPT], dr[EPT];
#pragma unroll
    for (int q = 0; q < EPT; q++) {
        int e = b0 + q * 1024 + t;
        int s = ei[e] & 1023, d = ei[ETOT + e] & 1023;   // graph-local ids
        sr[q] = s; dr[q] = d;
        sd[e] = ((unsigned)d << 16) | (unsigned)s;
        atomicAdd(&hs[s], 1);
        atomicAdd(&hc[d], 1);
    }
    __syncthreads();
    int v = hc[t];
    dv[t] = rsqrtf((float)hs[t] + 1.0f);
    int s = v;
#pragma unroll
    for (int off = 1; off < 64; off <<= 1) {
        int u = __shfl_up(s, off, 64);
        if (lane >= off) s += u;
    }
    if (lane == 63) wsum[wv] = s;
    __syncthreads();
    if (wv == 0) {
        int ws = (lane < 16) ? wsum[lane] : 0;
#pragma unroll
        for (int off = 1; off < 16; off <<= 1) {
            int u = __shfl_up(ws, off, 64);
            if (lane >= off) ws += u;
        }
        if (lane < 16) wsum[lane] = ws;
    }
    __syncthreads();
    int excl = b0 + s + ((wv > 0) ? wsum[wv - 1] : 0) - v;
    eoff[g * 1024 + t] = excl;
    cnt[g * 1024 + t] = v;
    dinv[g * 1024 + t] = dv[t];
    cur[t] = excl;
    __syncthreads();
#pragma unroll
    for (int q = 0; q < EPT; q++) {
        int pos = atomicAdd(&cur[dr[q]], 1);
        eidx[pos] = (ushortT)(g * 1024 + sr[q]);   // global row id < 65536
    }
    if (g == 0) {
        if (t < 128) shf[t] = pw0[t] * pw0[t];
        __syncthreads();
        for (int q = 64; q > 0; q >>= 1) {
            if (t < q) shf[t] += shf[t + q];
            __syncthreads();
        }
        if (t == 0) invn[0] = rsqrtf(shf[0]);
    }
}

// ------- linear (MFMA): xS = dinv .* ((gathered x)@W.T + b), fused prev-layer readout -------
__global__ __launch_bounds__(256) void linear_kernel(const float* __restrict__ x,
                              const __half* __restrict__ xA,
                              const int* __restrict__ perm, const float* __restrict__ sval,
                              const __half* __restrict__ W16, const float* __restrict__ b,
                              const float* __restrict__ dinvL,
                              __half* __restrict__ xH,
                              unsigned* __restrict__ maxbL, float* __restrict__ sumbL,
                              int n_prev, int kk, int cpg, int mode) {
    __shared__ float rmaxW[512], rsumW[512];   // [wave][128]
    int tid = threadIdx.x;
    int g   = blockIdx.x / cpg;
    int j0  = (blockIdx.x % cpg) * 64;
    int wv  = tid >> 6;          // wave 0..3 -> node group
    int l   = tid & 63;
    int l16 = l & 15;
    int kgrp = l >> 4;           // 0..3
    int jrow = j0 + wv * 16 + l16;   // node this lane carries in B-frag / stores
    bool valid = jrow < kk;
    // ---- build B-frags (4 x half8, one per 32-wide k block) ----
    f16x8 bf[4];
    if (mode) {
        int idx = g * kk + (valid ? jrow : 0);
        int rowg = perm[idx];
        float sc = valid ? sval[idx] : 0.f;
        const uint4* xrow = (const uint4*)(xA + (size_t)(g * n_prev + rowg) * DIM);
#pragma unroll
        for (int kb = 0; kb < 4; kb++) {
            uint4 hv = xrow[kb * 4 + kgrp];
            __half2* hp = (__half2*)&hv;
#pragma unroll
            for (int q = 0; q < 4; q++) {
                float2 f = __half22float2(hp[q]);
                hp[q] = __floats2half2_rn(f.x * sc, f.y * sc);
            }
            bf[kb] = *(f16x8*)&hv;
        }
    } else {
        const float* xrow = x + (size_t)(g * kk + jrow) * DIM;
#pragma unroll
        for (int kb = 0; kb < 4; kb++) {
            float4 a = *(const float4*)(xrow + kb * 32 + kgrp * 8);
            float4 c = *(const float4*)(xrow + kb * 32 + kgrp * 8 + 4);
            __half2 h0 = __floats2half2_rn(a.x, a.y), h1 = __floats2half2_rn(a.z, a.w);
            __half2 h2 = __floats2half2_rn(c.x, c.y), h3 = __floats2half2_rn(c.z, c.w);
            uint4 hv;
            hv.x = *(unsigned*)&h0; hv.y = *(unsigned*)&h1;
            hv.z = *(unsigned*)&h2; hv.w = *(unsigned*)&h3;
            bf[kb] = *(f16x8*)&hv;
        }
    }
    // ---- prev-layer readout from B-frags (mode 1): packed-f16 shuffle reduce over 16 nodes ----
    if (mode) {
#pragma unroll
        for (int kb = 0; kb < 4; kb++) {
            uint4 fv = *(uint4*)&bf[kb];
            uint4 mxv, smv;
            if (valid) { mxv = fv; smv = fv; }
            else {
                mxv = make_uint4(0xFC00FC00u, 0xFC00FC00u, 0xFC00FC00u, 0xFC00FC00u);
                smv = make_uint4(0u, 0u, 0u, 0u);
            }
#pragma unroll
            for (int st = 1; st < 16; st <<= 1) {
                uint4 om, os;
                om.x = __shfl_xor(mxv.x, st, 16); om.y = __shfl_xor(mxv.y, st, 16);
                om.z = __shfl_xor(mxv.z, st, 16); om.w = __shfl_xor(mxv.w, st, 16);
                os.x = __shfl_xor(smv.x, st, 16); os.y = __shfl_xor(smv.y, st, 16);
                os.z = __shfl_xor(smv.z, st, 16); os.w = __shfl_xor(smv.w, st, 16);
                mxv.x = hmax2u(mxv.x, om.x); mxv.y = hmax2u(mxv.y, om.y);
                mxv.z = hmax2u(mxv.z, om.z); mxv.w = hmax2u(mxv.w, om.w);
                smv.x = hadd2u(smv.x, os.x); smv.y = hadd2u(smv.y, os.y);
                smv.z = hadd2u(smv.z, os.z); smv.w = hadd2u(smv.w, os.w);
            }
            if (l16 == 0) {
                int cb = wv * 128 + kb * 32 + kgrp * 8;
                __half2* mh = (__half2*)&mxv;
                __half2* sh = (__half2*)&smv;
#pragma unroll
                for (int q = 0; q < 4; q++) {
                    float2 fm = __half22float2(mh[q]);
                    float2 fs = __half22float2(sh[q]);
                    rmaxW[cb + q * 2 + 0] = fm.x; rmaxW[cb + q * 2 + 1] = fm.y;
                    rsumW[cb + q * 2 + 0] = fs.x; rsumW[cb + q * 2 + 1] = fs.y;
                }
            }
        }
    }
    // ---- MFMA: acc[ft] over 8 feature tiles, K = 128 ----
    f32x4 acc[8];
#pragma unroll
    for (int ft = 0; ft < 8; ft++) {
        float4 bv = *(const float4*)(b + ft * 16 + kgrp * 4);
        f32x4 a; a[0] = bv.x; a[1] = bv.y; a[2] = bv.z; a[3] = bv.w;
        acc[ft] = a;
    }
    const uint4* wp = (const uint4*)W16;
#pragma unroll
    for (int kb = 0; kb < 4; kb++) {
#pragma unroll
        for (int ft = 0; ft < 8; ft++) {
            uint4 wfrag = wp[(ft * 16 + l16) * 16 + kb * 4 + kgrp];
            acc[ft] = __builtin_amdgcn_mfma_f32_16x16x32_f16(*(f16x8*)&wfrag, bf[kb],
                                                             acc[ft], 0, 0, 0);
        }
    }
    // ---- store xS = dinv*y in fp16: lane -> node jrow, features ft*16 + kgrp*4 + r ----
    if (valid) {
        float dsn = dinvL[g * kk + jrow];
        __half* yrow = xH + (size_t)(g * kk + jrow) * DIM;
#pragma unroll
        for (int ft = 0; ft < 8; ft++) {
            __half2 h0 = __floats2half2_rn(acc[ft][0] * dsn, acc[ft][1] * dsn);
            __half2 h1 = __floats2half2_rn(acc[ft][2] * dsn, acc[ft][3] * dsn);
            uint2 pk;
            pk.x = *(unsigned*)&h0; pk.y = *(unsigned*)&h1;
            *(uint2*)(yrow + ft * 16 + kgrp * 4) = pk;
        }
    }
    if (mode) {
        __syncthreads();
        if (tid < 128) {
            float m = rmaxW[tid], s = rsumW[tid];
#pragma unroll
            for (int w = 1; w < 4; w++) {
                m = fmaxf(m, rmaxW[w * 128 + tid]);
                s += rsumW[w * 128 + tid];
            }
            atomicMax(&maxbL[g * 128 + tid], fxform(m));
            atomicAdd(&sumbL[g * 128 + tid], s);
        }
    }
}

// --------- fused aggregate + self + relu + score (u16 edge list, f32 accumulate) ---------
// xH rows are pre-scaled by dinv (xS = d*x), so agg = d_dst * (sum of xS rows incl self).
// Round-15: descriptor prefetch restored (double-buffered D/F) -- the round-12 rewrite had
// dropped it, leaving desc-load -> gather as a serial 2x-latency chain per iteration.
#define ACC8(xv) { \
    float2 c0_ = __half22float2(*(const __half2*)&(xv).x); \
    float2 c1_ = __half22float2(*(const __half2*)&(xv).y); \
    float2 c2_ = __half22float2(*(const __half2*)&(xv).z); \
    float2 c3_ = __half22float2(*(const __half2*)&(xv).w); \
    a0[0] += c0_.x; a0[1] += c0_.y; a1[0] += c1_.x; a1[1] += c1_.y; \
    a2[0] += c2_.x; a2[1] += c2_.y; a3[0] += c3_.x; a3[1] += c3_.y; }

#define GATHER4(D0, D1) { \
    unsigned r0 = hi ? ((D0).x >> 16) : ((D0).x & 0xFFFFu); \
    unsigned r1 = hi ? ((D0).y >> 16) : ((D0).y & 0xFFFFu); \
    unsigned r2 = hi ? ((D1).x >> 16) : ((D1).x & 0xFFFFu); \
    unsigned r3 = hi ? ((D1).y >> 16) : ((D1).y & 0xFFFFu); \
    uint4 x0 = xr[r0 * 16u + sub]; \
    uint4 x1 = xr[r1 * 16u + sub]; \
    uint4 x2 = xr[r2 * 16u + sub]; \
    uint4 x3 = xr[r3 * 16u + sub]; \
    ACC8(x0); ACC8(x1); ACC8(x2); ACC8(x3); }

__global__ __launch_bounds__(256, 8) void fused_agg_kernel(
                                 const __half* __restrict__ xH, const ushortT* __restrict__ eidx,
                                 const int* __restrict__ eoff, const int* __restrict__ cnt,
                                 const float* __restrict__ dinv,
                                 const float* __restrict__ pw, const float* __restrict__ invn,
                                 __half* __restrict__ xA, float* __restrict__ score, int n) {
    int t = threadIdx.x;
    int g = blockIdx.x % NB;
    int chunk = blockIdx.x / NB;
    int ln = chunk * 8 + (t >> 5);
    if (ln >= n) return;
    int node = g * n + ln;
    int lane = t & 31;
    int sub = lane & 15;
    int hi  = lane >> 4;
    const uint4* __restrict__ xr = (const uint4*)xH;   // row = 16 uint4 (256 B)
    float dsn = dinv[node];
    f32x2 a0 = {0.f, 0.f}, a1 = {0.f, 0.f}, a2 = {0.f, 0.f}, a3 = {0.f, 0.f};
    // self term: lo half only
    if (!hi) {
        uint4 qs = xr[(unsigned)node * 16u + sub];
        ACC8(qs);
    }
    int s0 = eoff[node], s1 = s0 + cnt[node];
    int j = s0;
    while ((j & 3) && j < s1) {   // align to 8B for uint2 descriptor loads
        if (!hi) {
            uint4 xv = xr[(unsigned)eidx[j] * 16u + sub];
            ACC8(xv);
        }
        j++;
    }
    int nq = (s1 - j) >> 2;       // uint2 quads (4 edges each)
    int rem = (s1 - j) & 3;
    const uint2* __restrict__ e4 = (const uint2*)(eidx + j);
    int q = 0;
    if (nq >= 2) {
        uint2 D0 = e4[0], D1 = e4[1];
        q = 2; nq -= 2;
        while (nq >= 2) {
            uint2 F0 = e4[q], F1 = e4[q + 1];   // prefetch next 8 edges
            GATHER4(D0, D1);
            D0 = F0; D1 = F1;
            q += 2; nq -= 2;
        }
        GATHER4(D0, D1);
    }
    if (nq == 1) {
        uint2 D0 = e4[q];
        unsigned r0 = hi ? (D0.x >> 16) : (D0.x & 0xFFFFu);
        unsigned r1 = hi ? (D0.y >> 16) : (D0.y & 0xFFFFu);
        uint4 x0 = xr[r0 * 16u + sub];
        uint4 x1 = xr[r1 * 16u + sub];
        ACC8(x0); ACC8(x1);
    }
    for (int e = s1 - rem; e < s1; e++) {
        if (!hi) {
            uint4 xv = xr[(unsigned)eidx[e] * 16u + sub];
            ACC8(xv);
        }
    }
    float acc0 = a0[0], acc1 = a0[1], acc2 = a1[0], acc3 = a1[1];
    float acc4 = a2[0], acc5 = a2[1], acc6 = a3[0], acc7 = a3[1];
    acc0 += __shfl_xor(acc0, 16, 32); acc1 += __shfl_xor(acc1, 16, 32);
    acc2 += __shfl_xor(acc2, 16, 32); acc3 += __shfl_xor(acc3, 16, 32);
    acc4 += __shfl_xor(acc4, 16, 32); acc5 += __shfl_xor(acc5, 16, 32);
    acc6 += __shfl_xor(acc6, 16, 32); acc7 += __shfl_xor(acc7, 16, 32);
    acc0 = fmaxf(acc0 * dsn, 0.f); acc1 = fmaxf(acc1 * dsn, 0.f);
    acc2 = fmaxf(acc2 * dsn, 0.f); acc3 = fmaxf(acc3 * dsn, 0.f);
    acc4 = fmaxf(acc4 * dsn, 0.f); acc5 = fmaxf(acc5 * dsn, 0.f);
    acc6 = fmaxf(acc6 * dsn, 0.f); acc7 = fmaxf(acc7 * dsn, 0.f);
    if (!hi) {
        __half2 h0 = __floats2half2_rn(acc0, acc1);
        __half2 h1 = __floats2half2_rn(acc2, acc3);
        __half2 h2 = __floats2half2_rn(acc4, acc5);
        __half2 h3 = __floats2half2_rn(acc6, acc7);
        uint4 pk;
        pk.x = *(unsigned int*)&h0; pk.y = *(unsigned int*)&h1;
        pk.z = *(unsigned int*)&h2; pk.w = *(unsigned int*)&h3;
        ((uint4*)xA)[(unsigned)node * 16u + sub] = pk;
    }
    float4 pa = ((const float4*)pw)[sub * 2];
    float4 pb = ((const float4*)pw)[sub * 2 + 1];
    float dot = acc0 * pa.x + acc1 * pa.y + acc2 * pa.z + acc3 * pa.w
              + acc4 * pb.x + acc5 * pb.y + acc6 * pb.z + acc7 * pb.w;
#pragma unroll
    for (int off = 8; off >= 1; off >>= 1) dot += __shfl_xor(dot, off, 16);
    if (lane == 0) score[node] = tanhf(dot * invn[0]);
}

// ---------------- pool: sort -> perm/sval/nid + CSR rebuild (packed u16 edges) ----------------
__global__ __launch_bounds__(1024) void pool_kernel(const float* __restrict__ score,
                              int* __restrict__ permG, float* __restrict__ svalG,
                              unsigned* __restrict__ sd,
                              ushortT* __restrict__ eidx, int* __restrict__ eoff,
                              int* __restrict__ cnt, float* __restrict__ dinv,
                              const float* __restrict__ pwN, float* __restrict__ invn,
                              int n, int k, int last) {
    __shared__ float keyS[2][1024];
    __shared__ int idxS[2][1024];
    __shared__ int nid[1024];
    __shared__ int hs[1024], hc[1024], cur[1024];
    __shared__ float dv[1024];
    __shared__ float shf[128];
    __shared__ int wsum[16];
    int g = blockIdx.x, t = threadIdx.x;
    int lane = t & 63, wv = t >> 6;
    int b0 = g * EPG, gk = g * k;
    float k_r = (t < n) ? score[g * n + t] : -2.0f;
    int i_r = t;
    hs[t] = 0; hc[t] = 0;
    // preload sd as uint2 pairs: thread t covers edges b0 + q*2048 + 2t, +1
    uint2 sde[EPT / 2];
    if (!last) {
        const uint2* sd2 = (const uint2*)(sd + b0);
#pragma unroll
        for (int q = 0; q < EPT / 2; q++)
            sde[q] = sd2[q * 1024 + t];
    }
    int par = 0;
    for (unsigned ksz = 2; ksz <= 1024; ksz <<= 1) {
        for (unsigned jj = ksz >> 1; jj > 0; jj >>= 1) {
            float kq; int iq;
            if (jj >= 64) {
                keyS[par][t] = k_r; idxS[par][t] = i_r;
                __syncthreads();
                kq = keyS[par][t ^ jj]; iq = idxS[par][t ^ jj];
                par ^= 1;
            } else {
                kq = __shfl_xor(k_r, (int)jj, 64);
                iq = __shfl_xor(i_r, (int)jj, 64);
            }
            bool mineFirst = (k_r > kq) || (k_r == kq && i_r < iq);
            bool up = ((t & ksz) == 0);
            bool iAmLower = ((t & jj) == 0);
            bool keepMine = (iAmLower == up) ? mineFirst : !mineFirst;
            if (!keepMine) { k_r = kq; i_r = iq; }
        }
    }
    nid[i_r] = (t < (unsigned)k) ? t : -1;
    if (t < k) { permG[gk + t] = i_r; svalG[gk + t] = k_r; }
    __syncthreads();
    if (last) return;
    int sr[EPT], dr[EPT];
#pragma unroll
    for (int q = 0; q < EPT; q++) {
        int e = b0 + (q >> 1) * 2048 + 2 * t + (q & 1);
        unsigned v = (q & 1) ? sde[q >> 1].y : sde[q >> 1].x;
        int s2 = -1, d2 = -1;
        if (v != 0xFFFFFFFFu) {
            int sl = (int)(v & 0xFFFFu), dl = (int)(v >> 16);
            s2 = nid[sl];
            d2 = nid[dl];
            if (s2 >= 0 && d2 >= 0) {
                sd[e] = ((unsigned)d2 << 16) | (unsigned)s2;
                atomicAdd(&hs[s2], 1);
                atomicAdd(&hc[d2], 1);
            } else {
                sd[e] = 0xFFFFFFFFu;
                s2 = -1;
            }
        }
        sr[q] = s2; dr[q] = d2;
    }
    __syncthreads();
    int v = (t < k) ? hc[t] : 0;
    if (t < k) dv[t] = rsqrtf((float)hs[t] + 1.0f);
    int s = v;
#pragma unroll
    for (int off = 1; off < 64; off <<= 1) {
        int u = __shfl_up(s, off, 64);
        if (lane >= off) s += u;
    }
    if (lane == 63) wsum[wv] = s;
    __syncthreads();
    if (wv == 0) {
        int ws = (lane < 16) ? wsum[lane] : 0;
#pragma unroll
        for (int off = 1; off < 16; off <<= 1) {
            int u = __shfl_up(ws, off, 64);
            if (lane >= off) ws += u;
        }
        if (lane < 16) wsum[lane] = ws;
    }
    __syncthreads();
    if (t < k) {
        int excl = b0 + s + ((wv > 0) ? wsum[wv - 1] : 0) - v;
        eoff[gk + t] = excl;
        cnt[gk + t] = v;
        dinv[gk + t] = dv[t];
        cur[t] = excl;
    }
    __syncthreads();
#pragma unroll
    for (int q = 0; q < EPT; q++) {
        if (sr[q] >= 0) {
            int pos = atomicAdd(&cur[dr[q]], 1);
            eidx[pos] = (ushortT)(gk + sr[q]);
        }
    }
    if (g == 0) {
        if (t < 128) shf[t] = pwN[t] * pwN[t];
        __syncthreads();
        for (int q = 64; q > 0; q >>= 1) {
            if (t < q) shf[t] += shf[t + q];
            __syncthreads();
        }
        if (t == 0) invn[0] = rsqrtf(shf[0]);
    }
}

// ---------------- last-layer readout: max/sum of xA[perm]*s via atomics ----------------
__global__ __launch_bounds__(256) void gather_kernel(const __half* __restrict__ xA,
                                const int* __restrict__ permG, const float* __restrict__ svalG,
                                unsigned* __restrict__ maxbL, float* __restrict__ sumbL,
                                int n, int k) {
    __shared__ float4 smx[8][33];
    __shared__ float4 ssm[8][33];
    int t = threadIdx.x;
    int g = blockIdx.x % NB;
    int chunk = blockIdx.x / NB;
    int j = chunk * 8 + (t >> 5);
    int lane = t & 31;
    int ch = t >> 5;
    float4 mx = make_float4(-INFINITY, -INFINITY, -INFINITY, -INFINITY);
    float4 sm = make_float4(0.f, 0.f, 0.f, 0.f);
    if (j < k) {
        int row = permG[g * k + j];
        float s = svalG[g * k + j];
        uint2 hv = ((const uint2*)(xA + ((size_t)g * n + row) * DIM))[lane];
        float2 lo = __half22float2(*(const __half2*)&hv.x);
        float2 hi = __half22float2(*(const __half2*)&hv.y);
        float4 vv = make_float4(lo.x * s, lo.y * s, hi.x * s, hi.y * s);
        mx = vv; sm = vv;
    }
    smx[ch][lane] = mx;
    ssm[ch][lane] = sm;
    __syncthreads();
    for (int s = 4; s >= 1; s >>= 1) {
        if (ch < s) {
            float4 a = smx[ch][lane], bb = smx[ch + s][lane];
            a.x = fmaxf(a.x, bb.x); a.y = fmaxf(a.y, bb.y);
            a.z = fmaxf(a.z, bb.z); a.w = fmaxf(a.w, bb.w);
            smx[ch][lane] = a;
            float4 c = ssm[ch][lane], d = ssm[ch + s][lane];
            c.x += d.x; c.y += d.y; c.z += d.z; c.w += d.w;
            ssm[ch][lane] = c;
        }
        __syncthreads();
    }
    if (ch == 0) {
        float4 m = smx[0][lane];
        float4 s4 = ssm[0][lane];
        int f0 = g * 128 + lane * 4;
        atomicMax(&maxbL[f0 + 0], fxform(m.x));
        atomicMax(&maxbL[f0 + 1], fxform(m.y));
        atomicMax(&maxbL[f0 + 2], fxform(m.z));
        atomicMax(&maxbL[f0 + 3], fxform(m.w));
        atomicAdd(&sumbL[f0 + 0], s4.x);
        atomicAdd(&sumbL[f0 + 1], s4.y);
        atomicAdd(&sumbL[f0 + 2], s4.z);
        atomicAdd(&sumbL[f0 + 3], s4.w);
    }
}

// ---------------- head: combine 5-layer readouts + MLP + log_softmax ----------------
__global__ __launch_bounds__(128) void head_kernel(const unsigned* __restrict__ maxb,
                              const float* __restrict__ sumb,
                              const float* __restrict__ l1w, const float* __restrict__ l1b,
                              const float* __restrict__ l2w, const float* __restrict__ l2b,
                              const float* __restrict__ l3w, const float* __restrict__ l3b,
                              float* __restrict__ out) {
    __shared__ float hr[256], h1[128], h2[64], lz[2];
    int g = blockIdx.x, t = threadIdx.x;
    const float invk[5] = {1.f / 820.f, 1.f / 656.f, 1.f / 525.f, 1.f / 420.f, 1.f / 336.f};
    float mxs = 0.f, sms = 0.f;
#pragma unroll
    for (int L = 0; L < 5; L++) {
        mxs += fxinv(maxb[(L * NB + g) * 128 + t]);
        sms += sumb[(L * NB + g) * 128 + t] * invk[L];
    }
    hr[t] = mxs;
    hr[128 + t] = sms;
    __syncthreads();
    float a1 = l1b[t];
    for (int d = 0; d < 256; d++) a1 += hr[d] * l1w[t * 256 + d];
    h1[t] = fmaxf(a1, 0.f);
    __syncthreads();
    if (t < 64) {
        float a2 = l2b[t];
        for (int d = 0; d < 128; d++) a2 += h1[d] * l2w[t * 128 + d];
        h2[t] = fmaxf(a2, 0.f);
    }
    __syncthreads();
    if (t < 2) {
        float a3 = l3b[t];
        for (int d = 0; d < 64; d++) a3 += h2[d] * l3w[t * 64 + d];
        lz[t] = a3;
    }
    __syncthreads();
    if (t < 2) {
        float z0 = lz[0], z1 = lz[1];
        float m = fmaxf(z0, z1);
        float lse = m + logf(expf(z0 - m) + expf(z1 - m));
        out[g * 2 + t] = lz[t] - lse;
    }
}

extern "C" void kernel_launch(void* const* d_in, const int* in_sizes, int n_in,
                              void* d_out, int out_size, void* d_ws, size_t ws_size,
                              hipStream_t stream) {
    const float* x_in = (const float*)d_in[0];
    const int* edge_index = (const int*)d_in[1];
    const float *cw[5], *cb[5], *pw[5];
    for (int i = 0; i < 5; i++) {
        cw[i] = (const float*)d_in[3 + 3 * i];
        cb[i] = (const float*)d_in[4 + 3 * i];
        pw[i] = (const float*)d_in[5 + 3 * i];
    }
    const float* l1w = (const float*)d_in[18];
    const float* l1b = (const float*)d_in[19];
    const float* l2w = (const float*)d_in[20];
    const float* l2b = (const float*)d_in[21];
    const float* l3w = (const float*)d_in[22];
    const float* l3b = (const float*)d_in[23];
    float* out = (float*)d_out;

    char* w = (char*)d_ws;
    __half* xA    = (__half*)w; w += (size_t)65536 * DIM * 2;  // fp16 aggregated features
    __half* xH    = (__half*)w; w += (size_t)65536 * DIM * 2;  // fp16 pre-scaled linear output
    unsigned* sd  = (unsigned*)w; w += (size_t)ETOT * 4;       // packed (dst<<16)|src, local ids
    ushortT* eidx = (ushortT*)w; w += (size_t)ETOT * 2;        // CSR gather list (global u16)
    int*   cnt   = (int*)w;   w += (size_t)65536 * 4;
    int*   eoff  = (int*)w;   w += (size_t)65536 * 4;
    float* dinv  = (float*)w; w += (size_t)65536 * 4;
    float* score = (float*)w; w += (size_t)65536 * 4;
    int*   perm  = (int*)w;   w += (size_t)65536 * 4;
    float* sval  = (float*)w; w += (size_t)65536 * 4;
    unsigned* maxb = (unsigned*)w; w += (size_t)5 * NB * 128 * 4;
    float* sumb  = (float*)w; w += (size_t)5 * NB * 128 * 4;
    __half* W16  = (__half*)w; w += (size_t)5 * 16384 * 2;     // fp16 weights, 5 layers
    float* invn  = (float*)w; w += 4;

    init_kernel<<<NB, 1024, 0, stream>>>(edge_index, sd, eidx, eoff, cnt, dinv,
                                         invn, pw[0], maxb, sumb,
                                         cw[0], cw[1], cw[2], cw[3], cw[4], W16);

    for (int i = 0; i < 5; i++) {
        int n = NS_H[i], k = NS_H[i + 1];
        int cpg = (n + 63) / 64;
        int last = (i == 4) ? 1 : 0;

        linear_kernel<<<NB * cpg, 256, 0, stream>>>(
            x_in, xA, perm, sval, W16 + (size_t)i * 16384, cb[i], dinv, xH,
            (i > 0) ? maxb + (size_t)(i - 1) * NB * 128 : (unsigned*)maxb,
            (i > 0) ? sumb + (size_t)(i - 1) * NB * 128 : (float*)sumb,
            (i > 0) ? NS_H[i - 1] : 0, n, cpg, (i > 0) ? 1 : 0);

        int gpb = (n + 7) / 8;
        fused_agg_kernel<<<NB * gpb, 256, 0, stream>>>(xH, eidx, eoff, cnt, dinv, pw[i],
                                                       invn, xA, score, n);
        pool_kernel<<<NB, 1024, 0, stream>>>(score, perm, sval, sd, eidx, eoff,
                                             cnt, dinv, (i < 4) ? pw[i + 1] : pw[i], invn,
                                             n, k, last);
    }
    // layer-4 readout (selection from pool 4 over layer-4 aggregated features)
    int k4 = NS_H[5];
    int gpk = (k4 + 7) / 8;
    gather_kernel<<<NB * gpk, 256, 0, stream>>>(xA, perm, sval,
                                                maxb + (size_t)4 * NB * 128,
                                                sumb + (size_t)4 * NB * 128,
                                                NS_H[4], k4);
    head_kernel<<<NB, 128, 0, stream>>>(maxb, sumb, l1w, l1b, l2w, l2b, l3w, l3b, out);
}

// Round 16
// 442.493 us; speedup vs baseline: 1.0411x; 1.0411x over previous
//
#include <hip/hip_runtime.h>
#include <hip/hip_fp16.h>
#include <math.h>

#define NB 64
#define DIM 128
#define ETOT 1048576
#define EPG 16384   // edges-per-graph region (ETOT / NB)
#define EPT 16      // edges per thread in 1024-thread per-graph kernels

static const int NS_H[6] = {1024, 820, 656, 525, 420, 336};

typedef _Float16 f16x8 __attribute__((ext_vector_type(8)));
typedef float f32x4 __attribute__((ext_vector_type(4)));
typedef float f32x2 __attribute__((ext_vector_type(2)));
typedef unsigned short ushortT;

// order-preserving float->uint transform for atomicMax
__device__ __forceinline__ unsigned fxform(float f) {
    int b = __float_as_int(f);
    return (b >= 0) ? ((unsigned)b | 0x80000000u) : ~(unsigned)b;
}
__device__ __forceinline__ float fxinv(unsigned u) {
    int b = (u & 0x80000000u) ? (int)(u ^ 0x80000000u) : (int)~u;
    return __int_as_float(b);
}
// packed-half max/add via float roundtrip (no __hmax2/__hadd2 on this ROCm)
__device__ __forceinline__ unsigned hmax2u(unsigned a, unsigned b) {
    float2 fa = __half22float2(*(__half2*)&a);
    float2 fb = __half22float2(*(__half2*)&b);
    __half2 r = __floats2half2_rn(fmaxf(fa.x, fb.x), fmaxf(fa.y, fb.y));
    return *(unsigned*)&r;
}
__device__ __forceinline__ unsigned hadd2u(unsigned a, unsigned b) {
    float2 fa = __half22float2(*(__half2*)&a);
    float2 fb = __half22float2(*(__half2*)&b);
    __half2 r = __floats2half2_rn(fa.x + fb.x, fa.y + fb.y);
    return *(unsigned*)&r;
}

// ------- init: edges->sd(packed local), histogram, scan, scatter eidx(u16), dinv, invn, W->fp16 ---
__global__ __launch_bounds__(1024) void init_kernel(const int* __restrict__ ei,
                                  unsigned* __restrict__ sd,
                                  ushortT* __restrict__ eidx, int* __restrict__ eoff,
                                  int* __restrict__ cnt, float* __restrict__ dinv,
                                  float* __restrict__ invn, const float* __restrict__ pw0,
                                  unsigned* __restrict__ maxb, float* __restrict__ sumb,
                                  const float* __restrict__ cw0, const float* __restrict__ cw1,
                                  const float* __restrict__ cw2, const float* __restrict__ cw3,
                                  const float* __restrict__ cw4, __half* __restrict__ W16) {
    __shared__ int hs[1024], hc[1024], cur[1024];
    __shared__ float dv[1024];
    __shared__ float shf[128];
    __shared__ int wsum[16];
    int g = blockIdx.x, t = threadIdx.x;
    int lane = t & 63, wv = t >> 6;
    hs[t] = 0; hc[t] = 0;
    int idx = g * 1024 + t;
    if (idx < 5 * NB * 128) { maxb[idx] = 0x007FFFFFu; sumb[idx] = 0.f; }
    if (g < 5) {   // fp16 copy of this layer's weight matrix
        const float* wsrc = (g == 0) ? cw0 : (g == 1) ? cw1 : (g == 2) ? cw2
                           : (g == 3) ? cw3 : cw4;
        for (int i = t; i < 16384; i += 1024)
            W16[g * 16384 + i] = __float2half(wsrc[i]);
    }
    __syncthreads();
    int b0 = g * EPG;
    int sr[EPT], dr[EPT];
#pragma unroll
    for (int q = 0; q < EPT; q++) {
        int e = b0 + q * 1024 + t;
        int s = ei[e] & 1023, d = ei[ETOT + e] & 1023;   // graph-local ids
        sr[q] = s; dr[q] = d;
        sd[e] = ((unsigned)d << 16) | (unsigned)s;
        atomicAdd(&hs[s], 1);
        atomicAdd(&hc[d], 1);
    }
    __syncthreads();
    int v = hc[t];
    dv[t] = rsqrtf((float)hs[t] + 1.0f);
    int s = v;
#pragma unroll
    for (int off = 1; off < 64; off <<= 1) {
        int u = __shfl_up(s, off, 64);
        if (lane >= off) s += u;
    }
    if (lane == 63) wsum[wv] = s;
    __syncthreads();
    if (wv == 0) {
        int ws = (lane < 16) ? wsum[lane] : 0;
#pragma unroll
        for (int off = 1; off < 16; off <<= 1) {
            int u = __shfl_up(ws, off, 64);
            if (lane >= off) ws += u;
        }
        if (lane < 16) wsum[lane] = ws;
    }
    __syncthreads();
    int excl = b0 + s + ((wv > 0) ? wsum[wv - 1] : 0) - v;
    eoff[g * 1024 + t] = excl;
    cnt[g * 1024 + t] = v;
    dinv[g * 1024 + t] = dv[t];
    cur[t] = excl;
    __syncthreads();
#pragma unroll
    for (int q = 0; q < EPT; q++) {
        int pos = atomicAdd(&cur[dr[q]], 1);
        eidx[pos] = (ushortT)(g * 1024 + sr[q]);   // global row id < 65536
    }
    if (g == 0) {
        if (t < 128) shf[t] = pw0[t] * pw0[t];
        __syncthreads();
        for (int q = 64; q > 0; q >>= 1) {
            if (t < q) shf[t] += shf[t + q];
            __syncthreads();
        }
        if (t == 0) invn[0] = rsqrtf(shf[0]);
    }
}

// ------- linear (MFMA): xS = dinv .* ((gathered x)@W.T + b), fused prev-layer readout -------
__global__ __launch_bounds__(256) void linear_kernel(const float* __restrict__ x,
                              const __half* __restrict__ xA,
                              const int* __restrict__ perm, const float* __restrict__ sval,
                              const __half* __restrict__ W16, const float* __restrict__ b,
                              const float* __restrict__ dinvL,
                              __half* __restrict__ xH,
                              unsigned* __restrict__ maxbL, float* __restrict__ sumbL,
                              int n_prev, int kk, int cpg, int mode) {
    __shared__ float rmaxW[512], rsumW[512];   // [wave][128]
    int tid = threadIdx.x;
    int g   = blockIdx.x / cpg;
    int j0  = (blockIdx.x % cpg) * 64;
    int wv  = tid >> 6;          // wave 0..3 -> node group
    int l   = tid & 63;
    int l16 = l & 15;
    int kgrp = l >> 4;           // 0..3
    int jrow = j0 + wv * 16 + l16;   // node this lane carries in B-frag / stores
    bool valid = jrow < kk;
    // ---- build B-frags (4 x half8, one per 32-wide k block) ----
    f16x8 bf[4];
    if (mode) {
        int idx = g * kk + (valid ? jrow : 0);
        int rowg = perm[idx];
        float sc = valid ? sval[idx] : 0.f;
        const uint4* xrow = (const uint4*)(xA + (size_t)(g * n_prev + rowg) * DIM);
#pragma unroll
        for (int kb = 0; kb < 4; kb++) {
            uint4 hv = xrow[kb * 4 + kgrp];
            __half2* hp = (__half2*)&hv;
#pragma unroll
            for (int q = 0; q < 4; q++) {
                float2 f = __half22float2(hp[q]);
                hp[q] = __floats2half2_rn(f.x * sc, f.y * sc);
            }
            bf[kb] = *(f16x8*)&hv;
        }
    } else {
        const float* xrow = x + (size_t)(g * kk + jrow) * DIM;
#pragma unroll
        for (int kb = 0; kb < 4; kb++) {
            float4 a = *(const float4*)(xrow + kb * 32 + kgrp * 8);
            float4 c = *(const float4*)(xrow + kb * 32 + kgrp * 8 + 4);
            __half2 h0 = __floats2half2_rn(a.x, a.y), h1 = __floats2half2_rn(a.z, a.w);
            __half2 h2 = __floats2half2_rn(c.x, c.y), h3 = __floats2half2_rn(c.z, c.w);
            uint4 hv;
            hv.x = *(unsigned*)&h0; hv.y = *(unsigned*)&h1;
            hv.z = *(unsigned*)&h2; hv.w = *(unsigned*)&h3;
            bf[kb] = *(f16x8*)&hv;
        }
    }
    // ---- prev-layer readout from B-frags (mode 1): packed-f16 shuffle reduce over 16 nodes ----
    if (mode) {
#pragma unroll
        for (int kb = 0; kb < 4; kb++) {
            uint4 fv = *(uint4*)&bf[kb];
            uint4 mxv, smv;
            if (valid) { mxv = fv; smv = fv; }
            else {
                mxv = make_uint4(0xFC00FC00u, 0xFC00FC00u, 0xFC00FC00u, 0xFC00FC00u);
                smv = make_uint4(0u, 0u, 0u, 0u);
            }
#pragma unroll
            for (int st = 1; st < 16; st <<= 1) {
                uint4 om, os;
                om.x = __shfl_xor(mxv.x, st, 16); om.y = __shfl_xor(mxv.y, st, 16);
                om.z = __shfl_xor(mxv.z, st, 16); om.w = __shfl_xor(mxv.w, st, 16);
                os.x = __shfl_xor(smv.x, st, 16); os.y = __shfl_xor(smv.y, st, 16);
                os.z = __shfl_xor(smv.z, st, 16); os.w = __shfl_xor(smv.w, st, 16);
                mxv.x = hmax2u(mxv.x, om.x); mxv.y = hmax2u(mxv.y, om.y);
                mxv.z = hmax2u(mxv.z, om.z); mxv.w = hmax2u(mxv.w, om.w);
                smv.x = hadd2u(smv.x, os.x); smv.y = hadd2u(smv.y, os.y);
                smv.z = hadd2u(smv.z, os.z); smv.w = hadd2u(smv.w, os.w);
            }
            if (l16 == 0) {
                int cb = wv * 128 + kb * 32 + kgrp * 8;
                __half2* mh = (__half2*)&mxv;
                __half2* sh = (__half2*)&smv;
#pragma unroll
                for (int q = 0; q < 4; q++) {
                    float2 fm = __half22float2(mh[q]);
                    float2 fs = __half22float2(sh[q]);
                    rmaxW[cb + q * 2 + 0] = fm.x; rmaxW[cb + q * 2 + 1] = fm.y;
                    rsumW[cb + q * 2 + 0] = fs.x; rsumW[cb + q * 2 + 1] = fs.y;
                }
            }
        }
    }
    // ---- MFMA: acc[ft] over 8 feature tiles, K = 128 ----
    f32x4 acc[8];
#pragma unroll
    for (int ft = 0; ft < 8; ft++) {
        float4 bv = *(const float4*)(b + ft * 16 + kgrp * 4);
        f32x4 a; a[0] = bv.x; a[1] = bv.y; a[2] = bv.z; a[3] = bv.w;
        acc[ft] = a;
    }
    const uint4* wp = (const uint4*)W16;
#pragma unroll
    for (int kb = 0; kb < 4; kb++) {
#pragma unroll
        for (int ft = 0; ft < 8; ft++) {
            uint4 wfrag = wp[(ft * 16 + l16) * 16 + kb * 4 + kgrp];
            acc[ft] = __builtin_amdgcn_mfma_f32_16x16x32_f16(*(f16x8*)&wfrag, bf[kb],
                                                             acc[ft], 0, 0, 0);
        }
    }
    // ---- store xS = dinv*y in fp16: lane -> node jrow, features ft*16 + kgrp*4 + r ----
    if (valid) {
        float dsn = dinvL[g * kk + jrow];
        __half* yrow = xH + (size_t)(g * kk + jrow) * DIM;
#pragma unroll
        for (int ft = 0; ft < 8; ft++) {
            __half2 h0 = __floats2half2_rn(acc[ft][0] * dsn, acc[ft][1] * dsn);
            __half2 h1 = __floats2half2_rn(acc[ft][2] * dsn, acc[ft][3] * dsn);
            uint2 pk;
            pk.x = *(unsigned*)&h0; pk.y = *(unsigned*)&h1;
            *(uint2*)(yrow + ft * 16 + kgrp * 4) = pk;
        }
    }
    if (mode) {
        __syncthreads();
        if (tid < 128) {
            float m = rmaxW[tid], s = rsumW[tid];
#pragma unroll
            for (int w = 1; w < 4; w++) {
                m = fmaxf(m, rmaxW[w * 128 + tid]);
                s += rsumW[w * 128 + tid];
            }
            atomicMax(&maxbL[g * 128 + tid], fxform(m));
            atomicAdd(&sumbL[g * 128 + tid], s);
        }
    }
}

// --------- fused aggregate + self + relu + score (u16 edge list, f32 accumulate) ---------
// xH rows are pre-scaled by dinv (xS = d*x), so agg = d_dst * (sum of xS rows incl self).
#define ACC8(xv) { \
    float2 c0_ = __half22float2(*(const __half2*)&(xv).x); \
    float2 c1_ = __half22float2(*(const __half2*)&(xv).y); \
    float2 c2_ = __half22float2(*(const __half2*)&(xv).z); \
    float2 c3_ = __half22float2(*(const __half2*)&(xv).w); \
    a0[0] += c0_.x; a0[1] += c0_.y; a1[0] += c1_.x; a1[1] += c1_.y; \
    a2[0] += c2_.x; a2[1] += c2_.y; a3[0] += c3_.x; a3[1] += c3_.y; }

__global__ __launch_bounds__(256, 4) void fused_agg_kernel(
                                 const __half* __restrict__ xH, const ushortT* __restrict__ eidx,
                                 const int* __restrict__ eoff, const int* __restrict__ cnt,
                                 const float* __restrict__ dinv,
                                 const float* __restrict__ pw, const float* __restrict__ invn,
                                 __half* __restrict__ xA, float* __restrict__ score, int n) {
    int t = threadIdx.x;
    int g = blockIdx.x % NB;
    int chunk = blockIdx.x / NB;
    int ln = chunk * 8 + (t >> 5);
    if (ln >= n) return;
    int node = g * n + ln;
    int lane = t & 31;
    int sub = lane & 15;
    int hi  = lane >> 4;
    const uint4* __restrict__ xr = (const uint4*)xH;   // row = 16 uint4 (256 B)
    float dsn = dinv[node];
    f32x2 a0 = {0.f, 0.f}, a1 = {0.f, 0.f}, a2 = {0.f, 0.f}, a3 = {0.f, 0.f};
    // self term: lo half only
    if (!hi) {
        uint4 qs = xr[(unsigned)node * 16u + sub];
        ACC8(qs);
    }
    int s0 = eoff[node], s1 = s0 + cnt[node];
    int j = s0;
    while ((j & 3) && j < s1) {   // align to 8B for uint2 descriptor loads
        if (!hi) {
            uint4 xv = xr[(unsigned)eidx[j] * 16u + sub];
            ACC8(xv);
        }
        j++;
    }
    int nq = (s1 - j) >> 2;       // uint2 quads (4 edges each)
    int rem = (s1 - j) & 3;
    const uint2* __restrict__ e4 = (const uint2*)(eidx + j);
    int q = 0;
    while (nq >= 2) {             // 8 edges per iteration: 2 desc loads + 4 paired gathers
        uint2 D0 = e4[q], D1 = e4[q + 1];
        unsigned r0 = hi ? (D0.x >> 16) : (D0.x & 0xFFFFu);
        unsigned r1 = hi ? (D0.y >> 16) : (D0.y & 0xFFFFu);
        unsigned r2 = hi ? (D1.x >> 16) : (D1.x & 0xFFFFu);
        unsigned r3 = hi ? (D1.y >> 16) : (D1.y & 0xFFFFu);
        uint4 x0 = xr[r0 * 16u + sub];
        uint4 x1 = xr[r1 * 16u + sub];
        uint4 x2 = xr[r2 * 16u + sub];
        uint4 x3 = xr[r3 * 16u + sub];
        ACC8(x0); ACC8(x1); ACC8(x2); ACC8(x3);
        q += 2; nq -= 2;
    }
    if (nq == 1) {
        uint2 D0 = e4[q];
        unsigned r0 = hi ? (D0.x >> 16) : (D0.x & 0xFFFFu);
        unsigned r1 = hi ? (D0.y >> 16) : (D0.y & 0xFFFFu);
        uint4 x0 = xr[r0 * 16u + sub];
        uint4 x1 = xr[r1 * 16u + sub];
        ACC8(x0); ACC8(x1);
    }
    for (int e = s1 - rem; e < s1; e++) {
        if (!hi) {
            uint4 xv = xr[(unsigned)eidx[e] * 16u + sub];
            ACC8(xv);
        }
    }
    float acc0 = a0[0], acc1 = a0[1], acc2 = a1[0], acc3 = a1[1];
    float acc4 = a2[0], acc5 = a2[1], acc6 = a3[0], acc7 = a3[1];
    acc0 += __shfl_xor(acc0, 16, 32); acc1 += __shfl_xor(acc1, 16, 32);
    acc2 += __shfl_xor(acc2, 16, 32); acc3 += __shfl_xor(acc3, 16, 32);
    acc4 += __shfl_xor(acc4, 16, 32); acc5 += __shfl_xor(acc5, 16, 32);
    acc6 += __shfl_xor(acc6, 16, 32); acc7 += __shfl_xor(acc7, 16, 32);
    acc0 = fmaxf(acc0 * dsn, 0.f); acc1 = fmaxf(acc1 * dsn, 0.f);
    acc2 = fmaxf(acc2 * dsn, 0.f); acc3 = fmaxf(acc3 * dsn, 0.f);
    acc4 = fmaxf(acc4 * dsn, 0.f); acc5 = fmaxf(acc5 * dsn, 0.f);
    acc6 = fmaxf(acc6 * dsn, 0.f); acc7 = fmaxf(acc7 * dsn, 0.f);
    if (!hi) {
        __half2 h0 = __floats2half2_rn(acc0, acc1);
        __half2 h1 = __floats2half2_rn(acc2, acc3);
        __half2 h2 = __floats2half2_rn(acc4, acc5);
        __half2 h3 = __floats2half2_rn(acc6, acc7);
        uint4 pk;
        pk.x = *(unsigned int*)&h0; pk.y = *(unsigned int*)&h1;
        pk.z = *(unsigned int*)&h2; pk.w = *(unsigned int*)&h3;
        ((uint4*)xA)[(unsigned)node * 16u + sub] = pk;
    }
    float4 pa = ((const float4*)pw)[sub * 2];
    float4 pb = ((const float4*)pw)[sub * 2 + 1];
    float dot = acc0 * pa.x + acc1 * pa.y + acc2 * pa.z + acc3 * pa.w
              + acc4 * pb.x + acc5 * pb.y + acc6 * pb.z + acc7 * pb.w;
#pragma unroll
    for (int off = 8; off >= 1; off >>= 1) dot += __shfl_xor(dot, off, 16);
    if (lane == 0) score[node] = tanhf(dot * invn[0]);
}

// ---- pool: sort -> perm/sval/nid + CSR rebuild | (last) inline readout + MLP head ----
__global__ __launch_bounds__(1024) void pool_kernel(const float* __restrict__ score,
                              int* __restrict__ permG, float* __restrict__ svalG,
                              unsigned* __restrict__ sd,
                              ushortT* __restrict__ eidx, int* __restrict__ eoff,
                              int* __restrict__ cnt, float* __restrict__ dinv,
                              const float* __restrict__ pwN, float* __restrict__ invn,
                              const __half* __restrict__ xA,
                              const unsigned* __restrict__ maxb, const float* __restrict__ sumb,
                              const float* __restrict__ l1w, const float* __restrict__ l1b,
                              const float* __restrict__ l2w, const float* __restrict__ l2b,
                              const float* __restrict__ l3w, const float* __restrict__ l3b,
                              float* __restrict__ out,
                              int n, int k, int last) {
    __shared__ float keyS[2][1024];
    __shared__ int idxS[2][1024];
    __shared__ int nid[1024];
    __shared__ int hs[1024], hc[1024], cur[1024];
    __shared__ float dv[1024];
    __shared__ float shf[128];
    __shared__ int wsum[16];
    __shared__ float4 smax[32][33], ssm[32][33];
    __shared__ float hr[256], h1[128], h2[64], lz[2];
    int g = blockIdx.x, t = threadIdx.x;
    int lane = t & 63, wv = t >> 6;
    int b0 = g * EPG, gk = g * k;
    float k_r = (t < n) ? score[g * n + t] : -2.0f;
    int i_r = t;
    hs[t] = 0; hc[t] = 0;
    unsigned sde[EPT];
    if (!last) {
#pragma unroll
        for (int q = 0; q < EPT; q++) {
            int e = b0 + q * 1024 + t;
            sde[q] = sd[e];
        }
    }
    int par = 0;
    for (unsigned ksz = 2; ksz <= 1024; ksz <<= 1) {
        for (unsigned jj = ksz >> 1; jj > 0; jj >>= 1) {
            float kq; int iq;
            if (jj >= 64) {
                keyS[par][t] = k_r; idxS[par][t] = i_r;
                __syncthreads();
                kq = keyS[par][t ^ jj]; iq = idxS[par][t ^ jj];
                par ^= 1;
            } else {
                kq = __shfl_xor(k_r, (int)jj, 64);
                iq = __shfl_xor(i_r, (int)jj, 64);
            }
            bool mineFirst = (k_r > kq) || (k_r == kq && i_r < iq);
            bool up = ((t & ksz) == 0);
            bool iAmLower = ((t & jj) == 0);
            bool keepMine = (iAmLower == up) ? mineFirst : !mineFirst;
            if (!keepMine) { k_r = kq; i_r = iq; }
        }
    }
    nid[i_r] = (t < (unsigned)k) ? t : -1;
    keyS[0][t] = k_r; idxS[0][t] = i_r;
    if (!last && t < k) { permG[gk + t] = i_r; svalG[gk + t] = k_r; }
    __syncthreads();
    if (last) {
        // ---- inline layer-4 readout: max/mean over top-k rows of xA ----
        int lane4 = t & 31, ch = t >> 5;
        float4 mx = make_float4(-INFINITY, -INFINITY, -INFINITY, -INFINITY);
        float4 sm = make_float4(0.f, 0.f, 0.f, 0.f);
        for (int j = ch; j < k; j += 32) {
            int row = idxS[0][j];
            float sv = keyS[0][j];
            uint2 hv = ((const uint2*)(xA + ((size_t)(g * n + row)) * DIM))[lane4];
            float2 lo = __half22float2(*(const __half2*)&hv.x);
            float2 hi2 = __half22float2(*(const __half2*)&hv.y);
            float4 vv = make_float4(lo.x * sv, lo.y * sv, hi2.x * sv, hi2.y * sv);
            mx.x = fmaxf(mx.x, vv.x); mx.y = fmaxf(mx.y, vv.y);
            mx.z = fmaxf(mx.z, vv.z); mx.w = fmaxf(mx.w, vv.w);
            sm.x += vv.x; sm.y += vv.y; sm.z += vv.z; sm.w += vv.w;
        }
        smax[ch][lane4] = mx;
        ssm[ch][lane4] = sm;
        __syncthreads();
        for (int s2 = 16; s2 >= 1; s2 >>= 1) {
            if (ch < s2) {
                float4 a = smax[ch][lane4], bb = smax[ch + s2][lane4];
                a.x = fmaxf(a.x, bb.x); a.y = fmaxf(a.y, bb.y);
                a.z = fmaxf(a.z, bb.z); a.w = fmaxf(a.w, bb.w);
                smax[ch][lane4] = a;
                float4 c = ssm[ch][lane4], d = ssm[ch + s2][lane4];
                c.x += d.x; c.y += d.y; c.z += d.z; c.w += d.w;
                ssm[ch][lane4] = c;
            }
            __syncthreads();
        }
        // ---- combine 5-layer readouts (layers 0-3 from maxb/sumb, layer 4 inline) ----
        if (t < 128) {
            const float invk[4] = {1.f / 820.f, 1.f / 656.f, 1.f / 525.f, 1.f / 420.f};
            float mxs = ((const float*)&smax[0][t >> 2])[t & 3];
            float sms = ((const float*)&ssm[0][t >> 2])[t & 3] * (1.f / 336.f);
#pragma unroll
            for (int L = 0; L < 4; L++) {
                mxs += fxinv(maxb[(L * NB + g) * 128 + t]);
                sms += sumb[(L * NB + g) * 128 + t] * invk[L];
            }
            hr[t] = mxs;
            hr[128 + t] = sms;
        }
        __syncthreads();
        if (t < 128) {
            float a1 = l1b[t];
            for (int d = 0; d < 256; d++) a1 += hr[d] * l1w[t * 256 + d];
            h1[t] = fmaxf(a1, 0.f);
        }
        __syncthreads();
        if (t < 64) {
            float a2 = l2b[t];
            for (int d = 0; d < 128; d++) a2 += h1[d] * l2w[t * 128 + d];
            h2[t] = fmaxf(a2, 0.f);
        }
        __syncthreads();
        if (t < 2) {
            float a3 = l3b[t];
            for (int d = 0; d < 64; d++) a3 += h2[d] * l3w[t * 64 + d];
            lz[t] = a3;
        }
        __syncthreads();
        if (t < 2) {
            float z0 = lz[0], z1 = lz[1];
            float m = fmaxf(z0, z1);
            float lse = m + logf(expf(z0 - m) + expf(z1 - m));
            out[g * 2 + t] = lz[t] - lse;
        }
        return;
    }
    int sr[EPT], dr[EPT];
#pragma unroll
    for (int q = 0; q < EPT; q++) {
        int e = b0 + q * 1024 + t;
        unsigned v = sde[q];
        int s2 = -1, d2 = -1;
        if (v != 0xFFFFFFFFu) {
            int sl = (int)(v & 0xFFFFu), dl = (int)(v >> 16);
            s2 = nid[sl];
            d2 = nid[dl];
            if (s2 >= 0 && d2 >= 0) {
                sd[e] = ((unsigned)d2 << 16) | (unsigned)s2;
                atomicAdd(&hs[s2], 1);
                atomicAdd(&hc[d2], 1);
            } else {
                sd[e] = 0xFFFFFFFFu;
                s2 = -1;
            }
        }
        sr[q] = s2; dr[q] = d2;
    }
    __syncthreads();
    int v = (t < k) ? hc[t] : 0;
    if (t < k) dv[t] = rsqrtf((float)hs[t] + 1.0f);
    int s = v;
#pragma unroll
    for (int off = 1; off < 64; off <<= 1) {
        int u = __shfl_up(s, off, 64);
        if (lane >= off) s += u;
    }
    if (lane == 63) wsum[wv] = s;
    __syncthreads();
    if (wv == 0) {
        int ws = (lane < 16) ? wsum[lane] : 0;
#pragma unroll
        for (int off = 1; off < 16; off <<= 1) {
            int u = __shfl_up(ws, off, 64);
            if (lane >= off) ws += u;
        }
        if (lane < 16) wsum[lane] = ws;
    }
    __syncthreads();
    if (t < k) {
        int excl = b0 + s + ((wv > 0) ? wsum[wv - 1] : 0) - v;
        eoff[gk + t] = excl;
        cnt[gk + t] = v;
        dinv[gk + t] = dv[t];
        cur[t] = excl;
    }
    __syncthreads();
#pragma unroll
    for (int q = 0; q < EPT; q++) {
        if (sr[q] >= 0) {
            int pos = atomicAdd(&cur[dr[q]], 1);
            eidx[pos] = (ushortT)(gk + sr[q]);
        }
    }
    if (g == 0) {
        if (t < 128) shf[t] = pwN[t] * pwN[t];
        __syncthreads();
        for (int q = 64; q > 0; q >>= 1) {
            if (t < q) shf[t] += shf[t + q];
            __syncthreads();
        }
        if (t == 0) invn[0] = rsqrtf(shf[0]);
    }
}

extern "C" void kernel_launch(void* const* d_in, const int* in_sizes, int n_in,
                              void* d_out, int out_size, void* d_ws, size_t ws_size,
                              hipStream_t stream) {
    const float* x_in = (const float*)d_in[0];
    const int* edge_index = (const int*)d_in[1];
    const float *cw[5], *cb[5], *pw[5];
    for (int i = 0; i < 5; i++) {
        cw[i] = (const float*)d_in[3 + 3 * i];
        cb[i] = (const float*)d_in[4 + 3 * i];
        pw[i] = (const float*)d_in[5 + 3 * i];
    }
    const float* l1w = (const float*)d_in[18];
    const float* l1b = (const float*)d_in[19];
    const float* l2w = (const float*)d_in[20];
    const float* l2b = (const float*)d_in[21];
    const float* l3w = (const float*)d_in[22];
    const float* l3b = (const float*)d_in[23];
    float* out = (float*)d_out;

    char* w = (char*)d_ws;
    __half* xA    = (__half*)w; w += (size_t)65536 * DIM * 2;  // fp16 aggregated features
    __half* xH    = (__half*)w; w += (size_t)65536 * DIM * 2;  // fp16 pre-scaled linear output
    unsigned* sd  = (unsigned*)w; w += (size_t)ETOT * 4;       // packed (dst<<16)|src, local ids
    ushortT* eidx = (ushortT*)w; w += (size_t)ETOT * 2;        // CSR gather list (global u16)
    int*   cnt   = (int*)w;   w += (size_t)65536 * 4;
    int*   eoff  = (int*)w;   w += (size_t)65536 * 4;
    float* dinv  = (float*)w; w += (size_t)65536 * 4;
    float* score = (float*)w; w += (size_t)65536 * 4;
    int*   perm  = (int*)w;   w += (size_t)65536 * 4;
    float* sval  = (float*)w; w += (size_t)65536 * 4;
    unsigned* maxb = (unsigned*)w; w += (size_t)5 * NB * 128 * 4;
    float* sumb  = (float*)w; w += (size_t)5 * NB * 128 * 4;
    __half* W16  = (__half*)w; w += (size_t)5 * 16384 * 2;     // fp16 weights, 5 layers
    float* invn  = (float*)w; w += 4;

    init_kernel<<<NB, 1024, 0, stream>>>(edge_index, sd, eidx, eoff, cnt, dinv,
                                         invn, pw[0], maxb, sumb,
                                         cw[0], cw[1], cw[2], cw[3], cw[4], W16);

    for (int i = 0; i < 5; i++) {
        int n = NS_H[i], k = NS_H[i + 1];
        int cpg = (n + 63) / 64;
        int last = (i == 4) ? 1 : 0;

        linear_kernel<<<NB * cpg, 256, 0, stream>>>(
            x_in, xA, perm, sval, W16 + (size_t)i * 16384, cb[i], dinv, xH,
            (i > 0) ? maxb + (size_t)(i - 1) * NB * 128 : (unsigned*)maxb,
            (i > 0) ? sumb + (size_t)(i - 1) * NB * 128 : (float*)sumb,
            (i > 0) ? NS_H[i - 1] : 0, n, cpg, (i > 0) ? 1 : 0);

        int gpb = (n + 7) / 8;
        fused_agg_kernel<<<NB * gpb, 256, 0, stream>>>(xH, eidx, eoff, cnt, dinv, pw[i],
                                                       invn, xA, score, n);
        pool_kernel<<<NB, 1024, 0, stream>>>(score, perm, sval, sd, eidx, eoff,
                                             cnt, dinv, (i < 4) ? pw[i + 1] : pw[i], invn,
                                             xA, maxb, sumb,
                                             l1w, l1b, l2w, l2b, l3w, l3b, out,
                                             n, k, last);
    }
}